// Round 1
// baseline (29.939 us; speedup 1.0000x reference)
//
#include <hip/hip_runtime.h>

// Problem constants (match reference)
#define HH    128
#define WW    128
#define CDIM  4
#define DK    3
#define FDIM  4
#define DEPTH 16
#define DOUT  14
#define NB    4
#define HW    (HH * WW)          // 16384

// ---------------------------------------------------------------------------
// Kernel A: bsum[f,h,w] = sum_{c,dd} bias[f,0,c,dd,h,w]
// (bias contribution to the conv is independent of b and i)
// ---------------------------------------------------------------------------
__global__ __launch_bounds__(256) void bsum_kernel(const float* __restrict__ bias,
                                                   float* __restrict__ bsum) {
    int idx = blockIdx.x * 256 + threadIdx.x;     // over f*H*W = 65536
    int f  = idx >> 14;                           // / 16384
    int hw = idx & 16383;
    const float* bp = bias + f * (CDIM * DK * HW) + hw;
    float s = 0.f;
#pragma unroll
    for (int c = 0; c < CDIM; ++c)
#pragma unroll
        for (int dd = 0; dd < DK; ++dd)
            s += bp[c * (DK * HW) + dd * HW];
    bsum[idx] = s;
}

// ---------------------------------------------------------------------------
// Kernel B: fused Q computation + 3x3 box-sum + leaky ReLU.
// Each block: one (b, i, 8-row h-tile). Computes Q for 10 rows (halo) for all
// 4 filters into LDS, then 3x3 box sum -> output.
//   Q[f,g,w] = bsum[f,g,w] + sum_{c,dd} x[b,c,i+dd,g,w] * W[f,c,dd,g,w]
//   y[b,f,i,h,w] = leaky( sum_{dr,dc in 3x3, zero-pad} Q[f,h+dr-1,w+dc-1] )
// ---------------------------------------------------------------------------
__global__ __launch_bounds__(256) void linerconv_main(const float* __restrict__ x,
                                                      const float* __restrict__ wgt,
                                                      const float* __restrict__ bsum,
                                                      float* __restrict__ out) {
    const int blk  = blockIdx.x;
    const int tile = blk & 15;            // 16 h-tiles of 8 rows
    const int tmp  = blk >> 4;
    const int i    = tmp % DOUT;
    const int b    = tmp / DOUT;
    const int h0   = tile * 8;

    __shared__ float lds[FDIM][10][WW];   // 4 * 10 * 128 * 4B = 20 KB

    const int tid = threadIdx.x;

    // ---- Phase 1: fill 10 rows (g = h0-1 .. h0+8) of Q for all 4 filters ----
    // iter 0: rows 0..7  (row = tid>>5, q = tid&31, float4 at w = 4q)
    // iter 1: rows 8..9  (first 64 threads)
#pragma unroll
    for (int it = 0; it < 2; ++it) {
        int row = (it == 0) ? (tid >> 5) : (8 + (tid >> 5));
        int q   = tid & 31;
        bool active = (it == 0) || (tid < 64);
        if (active) {
            int g = h0 - 1 + row;
            if (g >= 0 && g < HH) {
                const int base_hw = g * WW + q * 4;
                // load x window: 12 float4 (shared across the 4 filters)
                float4 xv[CDIM][DK];
#pragma unroll
                for (int c = 0; c < CDIM; ++c)
#pragma unroll
                    for (int dd = 0; dd < DK; ++dd)
                        xv[c][dd] = *(const float4*)(x + b * (CDIM * DEPTH * HW)
                                                       + c * (DEPTH * HW)
                                                       + (i + dd) * HW + base_hw);
#pragma unroll
                for (int f = 0; f < FDIM; ++f) {
                    float4 a = *(const float4*)(bsum + f * HW + base_hw);
#pragma unroll
                    for (int c = 0; c < CDIM; ++c)
#pragma unroll
                        for (int dd = 0; dd < DK; ++dd) {
                            float4 wv = *(const float4*)(wgt + f * (CDIM * DK * HW)
                                                             + c * (DK * HW)
                                                             + dd * HW + base_hw);
                            a.x += xv[c][dd].x * wv.x;
                            a.y += xv[c][dd].y * wv.y;
                            a.z += xv[c][dd].z * wv.z;
                            a.w += xv[c][dd].w * wv.w;
                        }
                    *(float4*)&lds[f][row][q * 4] = a;
                }
            } else {
                float4 z = make_float4(0.f, 0.f, 0.f, 0.f);
#pragma unroll
                for (int f = 0; f < FDIM; ++f)
                    *(float4*)&lds[f][row][q * 4] = z;
            }
        }
    }
    __syncthreads();

    // ---- Phase 2: 3x3 box sum + leaky ReLU, write outputs ----
    // outputs: 4 f * 8 rows * 128 w = 4096 -> 16 per thread
    const int w  = tid & 127;
    const int r2 = tid >> 7;              // 0..1
#pragma unroll
    for (int f = 0; f < FDIM; ++f) {
#pragma unroll
        for (int rr = 0; rr < 4; ++rr) {
            const int orow = rr * 2 + r2; // 0..7 ; lds center row = orow+1
            float s = 0.f;
#pragma unroll
            for (int dr = 0; dr < 3; ++dr) {
                const float* Lr = lds[f][orow + dr];
                s += Lr[w];
                if (w > 0)   s += Lr[w - 1];
                if (w < 127) s += Lr[w + 1];
            }
            float y = (s >= 0.f) ? s : 0.2f * s;
            out[((b * FDIM + f) * DOUT + i) * HW + (h0 + orow) * WW + w] = y;
        }
    }
}

extern "C" void kernel_launch(void* const* d_in, const int* in_sizes, int n_in,
                              void* d_out, int out_size, void* d_ws, size_t ws_size,
                              hipStream_t stream) {
    const float* x    = (const float*)d_in[0];   // [4,4,16,128,128]
    const float* wgt  = (const float*)d_in[1];   // [4,1,4,3,128,128]
    const float* bias = (const float*)d_in[2];   // [4,1,4,3,128,128]
    float* out  = (float*)d_out;                 // [4,4,14,128,128]
    float* bsum = (float*)d_ws;                  // 65536 floats = 256 KB

    bsum_kernel<<<256, 256, 0, stream>>>(bias, bsum);
    linerconv_main<<<NB * DOUT * 16, 256, 0, stream>>>(x, wgt, bsum, out);
}

// Round 2
// 22.049 us; speedup vs baseline: 1.3579x; 1.3579x over previous
//
#include <hip/hip_runtime.h>

// Problem constants (match reference)
#define HH    128
#define WW    128
#define CDIM  4
#define DK    3
#define FDIM  4
#define DEPTH 16
#define DOUT  14
#define NB    4
#define HW    (HH * WW)          // 16384
#define IB    2                  // i-values per block
#define NIP   (DOUT / IB)        // 7

// ---------------------------------------------------------------------------
// Kernel A: bsum[f,h,w] = sum_{c,dd} bias[f,0,c,dd,h,w]
// ---------------------------------------------------------------------------
__global__ __launch_bounds__(256) void bsum_kernel(const float* __restrict__ bias,
                                                   float* __restrict__ bsum) {
    int idx = blockIdx.x * 256 + threadIdx.x;     // over f*H*W = 65536
    int f  = idx >> 14;
    int hw = idx & 16383;
    const float* bp = bias + f * (CDIM * DK * HW) + hw;
    float s = 0.f;
#pragma unroll
    for (int c = 0; c < CDIM; ++c)
#pragma unroll
        for (int dd = 0; dd < DK; ++dd)
            s += bp[c * (DK * HW) + dd * HW];
    bsum[idx] = s;
}

// ---------------------------------------------------------------------------
// Kernel B: fused Q + 3x3 box-sum + leaky ReLU, 2 depth-outputs per block.
//   Q[i2,f,g,w] = bsum[f,g,w] + sum_{c,dd} x[b,c,i0+i2+dd,g,w] * W[f,c,dd,g,w]
//   y = leaky( 3x3 zero-padded box sum of Q )
// Block: (b, i-pair, 8-row h-tile). Weights loaded once, applied to both i.
// ---------------------------------------------------------------------------
__global__ __launch_bounds__(256) void linerconv_main(const float* __restrict__ x,
                                                      const float* __restrict__ wgt,
                                                      const float* __restrict__ bsum,
                                                      float* __restrict__ out) {
    const int blk  = blockIdx.x;
    const int tile = blk & 15;              // 16 h-tiles of 8 rows
    const int tmp  = blk >> 4;
    const int ip   = tmp % NIP;
    const int b    = tmp / NIP;
    const int i0   = ip * IB;
    const int h0   = tile * 8;

    __shared__ float lds[IB][FDIM][10][WW]; // 40 KB

    const int tid = threadIdx.x;

    // ---- Phase 1: fill 10 halo rows of Q for both i and all 4 filters ----
    // 320 slots = 10 rows x 32 quads; iter0: rows 0..7, iter1: rows 8..9.
#pragma unroll
    for (int it = 0; it < 2; ++it) {
        int row = (it == 0) ? (tid >> 5) : (8 + (tid >> 5));
        int q   = tid & 31;
        bool active = (it == 0) || (tid < 64);
        if (active) {
            int g = h0 - 1 + row;
            if (g >= 0 && g < HH) {
                const int base_hw = g * WW + q * 4;
                float4 a0[FDIM], a1[FDIM];
#pragma unroll
                for (int f = 0; f < FDIM; ++f) {
                    float4 bv = *(const float4*)(bsum + f * HW + base_hw);
                    a0[f] = bv;
                    a1[f] = bv;
                }
                const float* xb = x + b * (CDIM * DEPTH * HW) + i0 * HW + base_hw;
                const float* wb = wgt + base_hw;
#pragma unroll
                for (int c = 0; c < CDIM; ++c) {
                    float4 xp[IB + DK - 1];     // planes i0 .. i0+3
#pragma unroll
                    for (int j = 0; j < IB + DK - 1; ++j)
                        xp[j] = *(const float4*)(xb + c * (DEPTH * HW) + j * HW);
#pragma unroll
                    for (int dd = 0; dd < DK; ++dd) {
#pragma unroll
                        for (int f = 0; f < FDIM; ++f) {
                            float4 wv = *(const float4*)(wb + f * (CDIM * DK * HW)
                                                            + c * (DK * HW) + dd * HW);
                            a0[f].x += xp[dd].x * wv.x;
                            a0[f].y += xp[dd].y * wv.y;
                            a0[f].z += xp[dd].z * wv.z;
                            a0[f].w += xp[dd].w * wv.w;
                            a1[f].x += xp[dd + 1].x * wv.x;
                            a1[f].y += xp[dd + 1].y * wv.y;
                            a1[f].z += xp[dd + 1].z * wv.z;
                            a1[f].w += xp[dd + 1].w * wv.w;
                        }
                    }
                }
#pragma unroll
                for (int f = 0; f < FDIM; ++f) {
                    *(float4*)&lds[0][f][row][q * 4] = a0[f];
                    *(float4*)&lds[1][f][row][q * 4] = a1[f];
                }
            } else {
                float4 z = make_float4(0.f, 0.f, 0.f, 0.f);
#pragma unroll
                for (int f = 0; f < FDIM; ++f) {
                    *(float4*)&lds[0][f][row][q * 4] = z;
                    *(float4*)&lds[1][f][row][q * 4] = z;
                }
            }
        }
    }
    __syncthreads();

    // ---- Phase 2: per-thread column box sum (rowsum reuse) + leaky ----
    // 1024 columns = 2 i x 4 f x 128 w; 256 threads -> 4 columns each.
    const int w = tid & 127;
    const int s = tid >> 7;                 // 0..1 (uniform per wave)
#pragma unroll
    for (int k = 0; k < 4; ++k) {
        const int i2 = k >> 1;
        const int f  = (k & 1) + s * 2;
        const float* Lb = &lds[i2][f][0][0];
        float rs[10];
#pragma unroll
        for (int g = 0; g < 10; ++g) {
            const float* Lr = Lb + g * WW;
            float v = Lr[w];
            if (w > 0)   v += Lr[w - 1];
            if (w < 127) v += Lr[w + 1];
            rs[g] = v;
        }
        float* op = out + ((b * FDIM + f) * DOUT + (i0 + i2)) * HW + h0 * WW + w;
#pragma unroll
        for (int r = 0; r < 8; ++r) {
            float sum = rs[r] + rs[r + 1] + rs[r + 2];
            float y = (sum >= 0.f) ? sum : 0.2f * sum;
            __builtin_nontemporal_store(y, op + r * WW);
        }
    }
}

extern "C" void kernel_launch(void* const* d_in, const int* in_sizes, int n_in,
                              void* d_out, int out_size, void* d_ws, size_t ws_size,
                              hipStream_t stream) {
    const float* x    = (const float*)d_in[0];   // [4,4,16,128,128]
    const float* wgt  = (const float*)d_in[1];   // [4,1,4,3,128,128]
    const float* bias = (const float*)d_in[2];   // [4,1,4,3,128,128]
    float* out  = (float*)d_out;                 // [4,4,14,128,128]
    float* bsum = (float*)d_ws;                  // 65536 floats = 256 KB

    bsum_kernel<<<256, 256, 0, stream>>>(bias, bsum);
    linerconv_main<<<NB * NIP * 16, 256, 0, stream>>>(x, wgt, bsum, out);
}

// Round 3
// 20.887 us; speedup vs baseline: 1.4334x; 1.0556x over previous
//
#include <hip/hip_runtime.h>

// Problem constants (match reference)
#define HH    128
#define WW    128
#define CDIM  4
#define DK    3
#define FDIM  4
#define DEPTH 16
#define DOUT  14
#define NB    4
#define HW    (HH * WW)          // 16384
#define IB    2                  // i-values per block
#define NIP   (DOUT / IB)        // 7
#define TROWS 4                  // output rows per block
#define HROWS (TROWS + 2)        // halo rows of Q per block
#define NTILE (HH / TROWS)       // 32 h-tiles

// ---------------------------------------------------------------------------
// Kernel A: bsum[f,h,w] = sum_{c,dd} bias[f,0,c,dd,h,w]
// ---------------------------------------------------------------------------
__global__ __launch_bounds__(256) void bsum_kernel(const float* __restrict__ bias,
                                                   float* __restrict__ bsum) {
    int idx = blockIdx.x * 256 + threadIdx.x;     // over f*H*W = 65536
    int f  = idx >> 14;
    int hw = idx & 16383;
    const float* bp = bias + f * (CDIM * DK * HW) + hw;
    float s = 0.f;
#pragma unroll
    for (int c = 0; c < CDIM; ++c)
#pragma unroll
        for (int dd = 0; dd < DK; ++dd)
            s += bp[c * (DK * HW) + dd * HW];
    bsum[idx] = s;
}

// ---------------------------------------------------------------------------
// Kernel B: fused Q + 3x3 box-sum + leaky ReLU.
// Block: (b, i-pair, 4-row h-tile). 6 halo rows of Q for 2 i and 4 filters
// into LDS (192 of 256 threads active in phase 1), then box sum + leaky.
// ---------------------------------------------------------------------------
__global__ __launch_bounds__(256) void linerconv_main(const float* __restrict__ x,
                                                      const float* __restrict__ wgt,
                                                      const float* __restrict__ bsum,
                                                      float* __restrict__ out) {
    const int blk  = blockIdx.x;
    const int tile = blk & (NTILE - 1);       // 32 h-tiles of 4 rows
    const int tmp  = blk >> 5;
    const int ip   = tmp % NIP;
    const int b    = tmp / NIP;
    const int i0   = ip * IB;
    const int h0   = tile * TROWS;

    __shared__ float lds[IB][FDIM][HROWS][WW]; // 2*4*6*128*4B = 24 KB

    const int tid = threadIdx.x;

    // ---- Phase 1: fill 6 halo rows of Q for both i and all 4 filters ----
    // 192 slots = 6 rows x 32 quads (threads 192..255 idle here).
    if (tid < HROWS * 32) {
        const int row = tid >> 5;             // 0..5
        const int q   = tid & 31;
        const int g   = h0 - 1 + row;
        if (g >= 0 && g < HH) {
            const int base_hw = g * WW + q * 4;
            float4 a0[FDIM], a1[FDIM];
#pragma unroll
            for (int f = 0; f < FDIM; ++f) {
                float4 bv = *(const float4*)(bsum + f * HW + base_hw);
                a0[f] = bv;
                a1[f] = bv;
            }
            const float* xb = x + b * (CDIM * DEPTH * HW) + i0 * HW + base_hw;
            const float* wb = wgt + base_hw;
#pragma unroll
            for (int c = 0; c < CDIM; ++c) {
                float4 xp[IB + DK - 1];       // planes i0 .. i0+3
#pragma unroll
                for (int j = 0; j < IB + DK - 1; ++j)
                    xp[j] = *(const float4*)(xb + c * (DEPTH * HW) + j * HW);
#pragma unroll
                for (int dd = 0; dd < DK; ++dd) {
#pragma unroll
                    for (int f = 0; f < FDIM; ++f) {
                        float4 wv = *(const float4*)(wb + f * (CDIM * DK * HW)
                                                        + c * (DK * HW) + dd * HW);
                        a0[f].x += xp[dd].x * wv.x;
                        a0[f].y += xp[dd].y * wv.y;
                        a0[f].z += xp[dd].z * wv.z;
                        a0[f].w += xp[dd].w * wv.w;
                        a1[f].x += xp[dd + 1].x * wv.x;
                        a1[f].y += xp[dd + 1].y * wv.y;
                        a1[f].z += xp[dd + 1].z * wv.z;
                        a1[f].w += xp[dd + 1].w * wv.w;
                    }
                }
            }
#pragma unroll
            for (int f = 0; f < FDIM; ++f) {
                *(float4*)&lds[0][f][row][q * 4] = a0[f];
                *(float4*)&lds[1][f][row][q * 4] = a1[f];
            }
        } else {
            float4 z = make_float4(0.f, 0.f, 0.f, 0.f);
#pragma unroll
            for (int f = 0; f < FDIM; ++f) {
                *(float4*)&lds[0][f][row][q * 4] = z;
                *(float4*)&lds[1][f][row][q * 4] = z;
            }
        }
    }
    __syncthreads();

    // ---- Phase 2: per-thread column box sum (rowsum reuse) + leaky ----
    // 1024 columns = 2 i x 4 f x 128 w; 256 threads -> 4 columns each.
    const int w = tid & 127;
    const int s = tid >> 7;                   // 0..1 (uniform per wave)
#pragma unroll
    for (int k = 0; k < 4; ++k) {
        const int i2 = k >> 1;
        const int f  = (k & 1) + s * 2;
        const float* Lb = &lds[i2][f][0][0];
        float rs[HROWS];
#pragma unroll
        for (int g = 0; g < HROWS; ++g) {
            const float* Lr = Lb + g * WW;
            float v = Lr[w];
            if (w > 0)   v += Lr[w - 1];
            if (w < 127) v += Lr[w + 1];
            rs[g] = v;
        }
        float* op = out + ((b * FDIM + f) * DOUT + (i0 + i2)) * HW + h0 * WW + w;
#pragma unroll
        for (int r = 0; r < TROWS; ++r) {
            float sum = rs[r] + rs[r + 1] + rs[r + 2];
            float y = (sum >= 0.f) ? sum : 0.2f * sum;
            __builtin_nontemporal_store(y, op + r * WW);
        }
    }
}

extern "C" void kernel_launch(void* const* d_in, const int* in_sizes, int n_in,
                              void* d_out, int out_size, void* d_ws, size_t ws_size,
                              hipStream_t stream) {
    const float* x    = (const float*)d_in[0];   // [4,4,16,128,128]
    const float* wgt  = (const float*)d_in[1];   // [4,1,4,3,128,128]
    const float* bias = (const float*)d_in[2];   // [4,1,4,3,128,128]
    float* out  = (float*)d_out;                 // [4,4,14,128,128]
    float* bsum = (float*)d_ws;                  // 65536 floats = 256 KB

    bsum_kernel<<<256, 256, 0, stream>>>(bias, bsum);
    linerconv_main<<<NB * NIP * NTILE, 256, 0, stream>>>(x, wgt, bsum, out);
}

// Round 5
// 18.499 us; speedup vs baseline: 1.6185x; 1.1291x over previous
//
#include <hip/hip_runtime.h>

// Problem constants (match reference)
#define HH    128
#define WW    128
#define CDIM  4
#define DK    3
#define FDIM  4
#define DEPTH 16
#define DOUT  14
#define NB    4
#define HW    (HH * WW)          // 16384
#define TROWS 4                  // output rows per block
#define HROWS (TROWS + 2)        // halo rows of Q per block
#define NTILE (HH / TROWS)       // 32 h-tiles
#define NIG   4                  // i-groups: {0-3,4-7,8-11,12-13(partial)}

typedef float nfloat4 __attribute__((ext_vector_type(4)));  // native vec for nt-store

// ---------------------------------------------------------------------------
// Kernel A: bsum[f,h,w] = sum_{c,dd} bias[f,0,c,dd,h,w]
// ---------------------------------------------------------------------------
__global__ __launch_bounds__(256) void bsum_kernel(const float* __restrict__ bias,
                                                   float* __restrict__ bsum) {
    int idx = blockIdx.x * 256 + threadIdx.x;     // over f*H*W = 65536
    int f  = idx >> 14;
    int hw = idx & 16383;
    const float* bp = bias + f * (CDIM * DK * HW) + hw;
    float s = 0.f;
#pragma unroll
    for (int c = 0; c < CDIM; ++c)
#pragma unroll
        for (int dd = 0; dd < DK; ++dd)
            s += bp[c * (DK * HW) + dd * HW];
    bsum[idx] = s;
}

// ---------------------------------------------------------------------------
// Kernel B: fused Q + 3x3 box-sum + leaky ReLU, 4 depth-outputs per block.
// Block: (b, i-group, 4-row h-tile). 6 halo rows of Q for 4 i and 4 filters
// into LDS, then vectorized box sum + leaky.
// ---------------------------------------------------------------------------
__global__ __launch_bounds__(256, 2) void linerconv_main(const float* __restrict__ x,
                                                         const float* __restrict__ wgt,
                                                         const float* __restrict__ bsum,
                                                         float* __restrict__ out) {
    const int blk  = blockIdx.x;
    const int tile = blk & (NTILE - 1);
    const int ig   = (blk >> 5) & (NIG - 1);
    const int b    = blk >> 7;
    const int i0   = ig * 4;                  // 0,4,8,12 (last group: 2 i only)
    const int h0   = tile * TROWS;
    const bool full = (ig != NIG - 1);

    __shared__ float lds[4][FDIM][HROWS][WW]; // [i2][f][row][w] = 48 KB

    const int tid = threadIdx.x;

    // ---- Phase 1: 192 threads fill HROWS x WW of Q for nI i and 4 f ----
    if (tid < HROWS * 32) {
        const int row = tid >> 5;             // 0..5
        const int q   = tid & 31;
        const int g   = h0 - 1 + row;
        if (g >= 0 && g < HH) {
            const int base_hw = g * WW + q * 4;
            const float* xb = x + (b * CDIM * DEPTH + i0) * HW + base_hw;
            const float* wb = wgt + base_hw;
            if (full) {
                float4 acc[4][FDIM];
#pragma unroll
                for (int f = 0; f < FDIM; ++f) {
                    float4 bv = *(const float4*)(bsum + f * HW + base_hw);
#pragma unroll
                    for (int i2 = 0; i2 < 4; ++i2) acc[i2][f] = bv;
                }
#pragma unroll
                for (int c = 0; c < CDIM; ++c) {
                    float4 xp[6];                 // planes i0 .. i0+5
#pragma unroll
                    for (int j = 0; j < 6; ++j)
                        xp[j] = *(const float4*)(xb + c * (DEPTH * HW) + j * HW);
#pragma unroll
                    for (int dd = 0; dd < DK; ++dd) {
#pragma unroll
                        for (int f = 0; f < FDIM; ++f) {
                            float4 wv = *(const float4*)(wb + ((f * CDIM + c) * DK + dd) * HW);
#pragma unroll
                            for (int i2 = 0; i2 < 4; ++i2) {
                                acc[i2][f].x += xp[i2 + dd].x * wv.x;
                                acc[i2][f].y += xp[i2 + dd].y * wv.y;
                                acc[i2][f].z += xp[i2 + dd].z * wv.z;
                                acc[i2][f].w += xp[i2 + dd].w * wv.w;
                            }
                        }
                    }
                }
#pragma unroll
                for (int i2 = 0; i2 < 4; ++i2)
#pragma unroll
                    for (int f = 0; f < FDIM; ++f)
                        *(float4*)&lds[i2][f][row][q * 4] = acc[i2][f];
            } else {
                // partial group: i = 12,13 -> planes 12..15 only
                float4 acc[2][FDIM];
#pragma unroll
                for (int f = 0; f < FDIM; ++f) {
                    float4 bv = *(const float4*)(bsum + f * HW + base_hw);
                    acc[0][f] = bv;
                    acc[1][f] = bv;
                }
#pragma unroll
                for (int c = 0; c < CDIM; ++c) {
                    float4 xp[4];
#pragma unroll
                    for (int j = 0; j < 4; ++j)
                        xp[j] = *(const float4*)(xb + c * (DEPTH * HW) + j * HW);
#pragma unroll
                    for (int dd = 0; dd < DK; ++dd) {
#pragma unroll
                        for (int f = 0; f < FDIM; ++f) {
                            float4 wv = *(const float4*)(wb + ((f * CDIM + c) * DK + dd) * HW);
#pragma unroll
                            for (int i2 = 0; i2 < 2; ++i2) {
                                acc[i2][f].x += xp[i2 + dd].x * wv.x;
                                acc[i2][f].y += xp[i2 + dd].y * wv.y;
                                acc[i2][f].z += xp[i2 + dd].z * wv.z;
                                acc[i2][f].w += xp[i2 + dd].w * wv.w;
                            }
                        }
                    }
                }
#pragma unroll
                for (int i2 = 0; i2 < 2; ++i2)
#pragma unroll
                    for (int f = 0; f < FDIM; ++f)
                        *(float4*)&lds[i2][f][row][q * 4] = acc[i2][f];
            }
        } else {
            float4 z = make_float4(0.f, 0.f, 0.f, 0.f);
#pragma unroll
            for (int i2 = 0; i2 < 4; ++i2)
#pragma unroll
                for (int f = 0; f < FDIM; ++f)
                    *(float4*)&lds[i2][f][row][q * 4] = z;
        }
    }
    __syncthreads();

    // ---- Phase 2: vectorized column box sums + leaky, float4 nt-stores ----
    // quad-columns: (i2, f, q); full: 512 -> 2/thread, partial: 256 -> 1.
    auto do_quadcol = [&](int idx) {
        const int q  = idx & 31;
        const int f  = (idx >> 5) & 3;
        const int i2 = idx >> 7;
        const float* Lb = &lds[i2][f][0][0];
        float4 rs[HROWS];
#pragma unroll
        for (int g = 0; g < HROWS; ++g) {
            const float* Lr = Lb + g * WW;
            float4 m  = *(const float4*)(Lr + q * 4);
            float lft = (q > 0)  ? Lr[q * 4 - 1] : 0.f;
            float rgt = (q < 31) ? Lr[q * 4 + 4] : 0.f;
            rs[g].x = lft + m.x + m.y;
            rs[g].y = m.x + m.y + m.z;
            rs[g].z = m.y + m.z + m.w;
            rs[g].w = m.z + m.w + rgt;
        }
        float* op = out + ((b * FDIM + f) * DOUT + (i0 + i2)) * HW + h0 * WW + q * 4;
#pragma unroll
        for (int r = 0; r < TROWS; ++r) {
            nfloat4 s;
            s.x = rs[r].x + rs[r + 1].x + rs[r + 2].x;
            s.y = rs[r].y + rs[r + 1].y + rs[r + 2].y;
            s.z = rs[r].z + rs[r + 1].z + rs[r + 2].z;
            s.w = rs[r].w + rs[r + 1].w + rs[r + 2].w;
            s.x = (s.x >= 0.f) ? s.x : 0.2f * s.x;
            s.y = (s.y >= 0.f) ? s.y : 0.2f * s.y;
            s.z = (s.z >= 0.f) ? s.z : 0.2f * s.z;
            s.w = (s.w >= 0.f) ? s.w : 0.2f * s.w;
            __builtin_nontemporal_store(s, (nfloat4*)(op + r * WW));
        }
    };
    do_quadcol(tid);
    if (full) do_quadcol(tid + 256);

}

extern "C" void kernel_launch(void* const* d_in, const int* in_sizes, int n_in,
                              void* d_out, int out_size, void* d_ws, size_t ws_size,
                              hipStream_t stream) {
    const float* x    = (const float*)d_in[0];   // [4,4,16,128,128]
    const float* wgt  = (const float*)d_in[1];   // [4,1,4,3,128,128]
    const float* bias = (const float*)d_in[2];   // [4,1,4,3,128,128]
    float* out  = (float*)d_out;                 // [4,4,14,128,128]
    float* bsum = (float*)d_ws;                  // 65536 floats = 256 KB

    bsum_kernel<<<256, 256, 0, stream>>>(bias, bsum);
    linerconv_main<<<NB * NIG * NTILE, 256, 0, stream>>>(x, wgt, bsum, out);
}